// Round 1
// baseline (2398.664 us; speedup 1.0000x reference)
//
#include <hip/hip_runtime.h>
#include <hip/hip_bf16.h>
#include <math.h>

#define D 256
#define NH 8
#define DH 32
#define LYR 2
#define G 64
#define KK 4096
#define T 4
#define EC 32
#define B 4
#define N 512
#define CITY 256
#define DFF 1024
#define NS 513   // N + 1 bs token

__device__ __forceinline__ float gelu_f(float x) {
    const float c = 0.7978845608028654f; // sqrt(2/pi)
    float x3 = x * x * x;
    return 0.5f * x * (1.f + tanhf(c * (x + 0.044715f * x3)));
}

// ---------------- token MLPs (meas + bs) -> src, src_xy ----------------
__global__ void tok_mlp_k(const float* __restrict__ meas_xy, const float* __restrict__ meas_v,
                          const float* __restrict__ bs_xy,
                          const float* __restrict__ mp_w1, const float* __restrict__ mp_b1,
                          const float* __restrict__ mp_w2, const float* __restrict__ mp_b2,
                          const float* __restrict__ bp_w1, const float* __restrict__ bp_b1,
                          const float* __restrict__ bp_w2, const float* __restrict__ bp_b2,
                          float* __restrict__ src, float* __restrict__ src_xy) {
    int id = blockIdx.x;
    int d = threadIdx.x;
    __shared__ float hid[D];
    int row;
    const float *w1, *b1, *w2, *b2;
    float x0, x1, x2 = 0.f;
    int nin;
    if (id < B * N) {
        int b = id >> 9, n = id & 511;
        x0 = meas_xy[(b * N + n) * 2 + 0];
        x1 = meas_xy[(b * N + n) * 2 + 1];
        x2 = meas_v[b * N + n];
        w1 = mp_w1; b1 = mp_b1; w2 = mp_w2; b2 = mp_b2; nin = 3;
        row = b * NS + n;
    } else {
        int b = id - B * N;
        x0 = bs_xy[b * 2 + 0];
        x1 = bs_xy[b * 2 + 1];
        w1 = bp_w1; b1 = bp_b1; w2 = bp_w2; b2 = bp_b2; nin = 2;
        row = b * NS + N;
    }
    float h = x0 * w1[d] + x1 * w1[D + d] + b1[d];
    if (nin == 3) h += x2 * w1[2 * D + d];
    hid[d] = gelu_f(h);
    __syncthreads();
    float o = b2[d];
    for (int j = 0; j < D; j++) o += hid[j] * w2[j * D + d];
    src[(size_t)row * D + d] = o;
    if (d == 0) { src_xy[row * 2 + 0] = x0; src_xy[row * 2 + 1] = x1; }
}

// ---------------- gaussian density [B,K] ----------------
__global__ void density_k(const float* __restrict__ meas_xy, float* __restrict__ dens) {
    int b = blockIdx.x >> 4, kc = blockIdx.x & 15;
    int k = kc * 256 + threadIdx.x;
    __shared__ float mx[N], my[N];
    for (int i = threadIdx.x; i < N; i += 256) {
        mx[i] = meas_xy[(b * N + i) * 2 + 0];
        my[i] = meas_xy[(b * N + i) * 2 + 1];
    }
    __syncthreads();
    float gx = ((k & 63) + 0.5f) / 64.f;
    float gy = ((k >> 6) + 0.5f) / 64.f;
    float s = 0.f;
    for (int n = 0; n < N; n++) {
        float dx = gx - mx[n], dy = gy - my[n];
        s += __expf(-(dx * dx + dy * dy) * 78.125f); // 1/(2*0.08^2)
    }
    dens[b * KK + k] = s * (1.f / (float)N);
}

// ---------------- env CNN ----------------
__global__ void conv1_k(const float* __restrict__ city, const float* __restrict__ w,
                        const float* __restrict__ bias, float* __restrict__ h1) {
    int i = blockIdx.x * 256 + threadIdx.x;   // ((b*EC+c)*4096 + y*64 + x)
    int x = i & 63, y = (i >> 6) & 63, c = (i >> 12) & 31, b = i >> 17;
    float s = bias[c];
    for (int ky = 0; ky < 3; ky++) {
        int yy = y + ky - 1;
        if (yy < 0 || yy >= G) continue;
        for (int kx = 0; kx < 3; kx++) {
            int xx = x + kx - 1;
            if (xx < 0 || xx >= G) continue;
            s += city[(b * CITY + yy * 4) * CITY + xx * 4] * w[c * 9 + ky * 3 + kx];
        }
    }
    h1[i] = gelu_f(s);
}

__global__ void conv2_k(const float* __restrict__ h1, const float* __restrict__ w,
                        const float* __restrict__ bias, float* __restrict__ h2) {
    int i = blockIdx.x * 256 + threadIdx.x;
    int x = i & 63, y = (i >> 6) & 63, c = (i >> 12) & 31, b = i >> 17;
    float s = bias[c];
    for (int ci = 0; ci < EC; ci++) {
        const float* hp = h1 + (((size_t)b * EC + ci) << 12);
        const float* wp = w + (c * EC + ci) * 9;
        for (int ky = 0; ky < 3; ky++) {
            int yy = y + ky - 1;
            if (yy < 0 || yy >= G) continue;
            for (int kx = 0; kx < 3; kx++) {
                int xx = x + kx - 1;
                if (xx < 0 || xx >= G) continue;
                s += hp[yy * G + xx] * wp[ky * 3 + kx];
            }
        }
    }
    h2[i] = gelu_f(s);
}

// ---------------- task vector ----------------
__global__ void tvec_k(const float* __restrict__ task_emb, const int* __restrict__ task_id,
                       const float* __restrict__ tp_w, const float* __restrict__ tp_b,
                       float* __restrict__ tvec) {
    int b = blockIdx.x, d = threadIdx.x;
    __shared__ float e[D];
    e[d] = task_emb[task_id[b] * D + d];
    __syncthreads();
    float s = tp_b[d];
    for (int j = 0; j < D; j++) s += e[j] * tp_w[j * D + d];
    tvec[b * D + d] = s;
}

// ---------------- grid init: grid_pos + task_vec + env conv3 ----------------
__global__ void grid_init_k(const float* __restrict__ h2, const float* __restrict__ w3,
                            const float* __restrict__ b3, const float* __restrict__ grid_pos,
                            const float* __restrict__ tvec, float* __restrict__ grid) {
    size_t i = (size_t)blockIdx.x * 256 + threadIdx.x;  // B*K*D
    int d = i & 255;
    size_t bk = i >> 8;
    int k = (int)(bk & 4095), b = (int)(bk >> 12);
    float s = b3[d];
    for (int ci = 0; ci < EC; ci++)
        s += h2[(((size_t)b * EC + ci) << 12) + k] * w3[d * EC + ci];
    grid[i] = s + grid_pos[(size_t)k * D + d] + tvec[b * D + d];
}

// ---------------- density injection (in place) ----------------
__global__ void dens_inject_k(float* __restrict__ grid, const float* __restrict__ dens,
                              const float* __restrict__ dw, const float* __restrict__ db) {
    size_t i = (size_t)blockIdx.x * 256 + threadIdx.x;
    int d = i & 255;
    size_t bk = i >> 8;
    grid[i] += dens[bk] * dw[d] + db[d];
}

// ---------------- layernorm ----------------
__global__ void ln_k(const float* __restrict__ x, const float* __restrict__ w,
                     const float* __restrict__ b, float* __restrict__ y) {
    size_t t = blockIdx.x;
    int d = threadIdx.x;
    float v = x[t * D + d];
    __shared__ float red[D];
    red[d] = v;
    __syncthreads();
    for (int s = 128; s > 0; s >>= 1) { if (d < s) red[d] += red[d + s]; __syncthreads(); }
    float mean = red[0] * (1.f / D);
    __syncthreads();
    float c = v - mean;
    red[d] = c * c;
    __syncthreads();
    for (int s = 128; s > 0; s >>= 1) { if (d < s) red[d] += red[d + s]; __syncthreads(); }
    float var = red[0] * (1.f / D);
    y[t * D + d] = c * rsqrtf(var + 1e-5f) * w[d] + b[d];
}

// ---------------- tiled GEMM: C[M,N] = A[M,Kd] @ W[Kd,N] + bias (opt GELU / accumulate) ----------------
template <int GELU, int ACCUM>
__global__ void gemm_k(const float* __restrict__ A, const float* __restrict__ W,
                       const float* __restrict__ bias, float* __restrict__ C,
                       int M, int Kd, int Nn) {
    __shared__ float As[16][64];
    __shared__ float Ws[16][64];
    int bn = blockIdx.x * 64;
    int bm = blockIdx.y * 64;
    int tid = threadIdx.x;
    int tx = tid & 15, ty = tid >> 4;
    float acc[4][4] = {};
    for (int k0 = 0; k0 < Kd; k0 += 16) {
        #pragma unroll
        for (int i = 0; i < 4; i++) {
            int li = tid * 4 + i;
            int r = li >> 4, c = li & 15;
            int gr = bm + r;
            As[c][r] = (gr < M) ? A[(size_t)gr * Kd + k0 + c] : 0.f;
        }
        #pragma unroll
        for (int i = 0; i < 4; i++) {
            int li = tid * 4 + i;
            int r = li >> 6, c = li & 63;
            Ws[r][c] = W[(size_t)(k0 + r) * Nn + bn + c];
        }
        __syncthreads();
        #pragma unroll
        for (int kk = 0; kk < 16; kk++) {
            float a[4], w[4];
            #pragma unroll
            for (int i = 0; i < 4; i++) a[i] = As[kk][ty * 4 + i];
            #pragma unroll
            for (int j = 0; j < 4; j++) w[j] = Ws[kk][tx * 4 + j];
            #pragma unroll
            for (int i = 0; i < 4; i++)
                #pragma unroll
                for (int j = 0; j < 4; j++) acc[i][j] += a[i] * w[j];
        }
        __syncthreads();
    }
    #pragma unroll
    for (int i = 0; i < 4; i++) {
        int gr = bm + ty * 4 + i;
        if (gr >= M) continue;
        #pragma unroll
        for (int j = 0; j < 4; j++) {
            int gc = bn + tx * 4 + j;
            float v = acc[i][j] + bias[gc];
            if (GELU) v = gelu_f(v);
            if (ACCUM) C[(size_t)gr * Nn + gc] += v;
            else C[(size_t)gr * Nn + gc] = v;
        }
    }
}

// ---------------- flash-style cross attention with distance bias ----------------
__global__ void attn_k(const float* __restrict__ q, const float* __restrict__ kkb,
                       const float* __restrict__ vvb, const float* __restrict__ sxy,
                       float* __restrict__ out) {
    int bid = blockIdx.x;                 // ((b*NH + h)*16 + kc)
    int kc = bid & 15, h = (bid >> 4) & 7, b = bid >> 7;
    int tid = threadIdx.x;
    int k = kc * 256 + tid;
    float gx = ((k & 63) + 0.5f) / 64.f;
    float gy = ((k >> 6) + 0.5f) / 64.f;
    float qv[DH];
    const float* qp = q + ((size_t)(b * KK + k)) * D + h * DH;
    #pragma unroll
    for (int j = 0; j < DH; j++) qv[j] = qp[j];
    float m = -1e30f, l = 0.f;
    float acc[DH] = {};
    __shared__ float ks[128][DH];
    __shared__ float vs[128][DH];
    __shared__ float sx[128], sy[128];
    const float inv_sqrt = 0.17677669529663687f; // 1/sqrt(32)
    for (int n0 = 0; n0 < NS; n0 += 128) {
        int cnt = min(128, NS - n0);
        __syncthreads();
        for (int i = tid; i < cnt * DH; i += 256) {
            int n = i >> 5, j = i & 31;
            size_t base = ((size_t)(b * NS + n0 + n)) * D + h * DH + j;
            ks[n][j] = kkb[base];
            vs[n][j] = vvb[base];
        }
        for (int i = tid; i < cnt; i += 256) {
            sx[i] = sxy[(b * NS + n0 + i) * 2 + 0];
            sy[i] = sxy[(b * NS + n0 + i) * 2 + 1];
        }
        __syncthreads();
        for (int n = 0; n < cnt; n++) {
            float s = 0.f;
            #pragma unroll
            for (int j = 0; j < DH; j++) s += qv[j] * ks[n][j];
            float dx = gx - sx[n], dy = gy - sy[n];
            s = s * inv_sqrt - sqrtf(dx * dx + dy * dy);
            float mn = fmaxf(m, s);
            float scale = __expf(m - mn);
            float p = __expf(s - mn);
            l = l * scale + p;
            #pragma unroll
            for (int j = 0; j < DH; j++) acc[j] = acc[j] * scale + p * vs[n][j];
            m = mn;
        }
    }
    float inv = 1.f / l;
    float* op = out + ((size_t)(b * KK + k)) * D + h * DH;
    #pragma unroll
    for (int j = 0; j < DH; j++) op[j] = acc[j] * inv;
}

// ---------------- fused tfp + head ----------------
__global__ void head_k(const float* __restrict__ grid, const int* __restrict__ task_id,
                       const float* __restrict__ tfp_w, const float* __restrict__ tfp_b,
                       const float* __restrict__ head_w, const float* __restrict__ head_b,
                       float* __restrict__ out) {
    int bk = blockIdx.x;
    int b = bk >> 12;
    int h = threadIdx.x;
    __shared__ float g[D];
    __shared__ float red[D];
    g[h] = grid[(size_t)bk * D + h];
    __syncthreads();
    int t = task_id[b];
    const float* wp = tfp_w + (size_t)t * D * D;
    float s = tfp_b[t * D + h];
    for (int j = 0; j < D; j++) s += g[j] * wp[j * D + h];
    s = gelu_f(s) * head_w[h];
    red[h] = s;
    __syncthreads();
    for (int st = 128; st > 0; st >>= 1) { if (h < st) red[h] += red[h + st]; __syncthreads(); }
    if (h == 0) out[bk] = red[0] + head_b[0];
}

extern "C" void kernel_launch(void* const* d_in, const int* in_sizes, int n_in,
                              void* d_out, int out_size, void* d_ws, size_t ws_size,
                              hipStream_t stream) {
    const float* meas_xy = (const float*)d_in[0];
    const float* meas_v  = (const float*)d_in[1];
    const float* bs_xy   = (const float*)d_in[2];
    const int*   task_id = (const int*)d_in[3];
    const float* city    = (const float*)d_in[4];
    const float* mp_w1 = (const float*)d_in[5];  const float* mp_b1 = (const float*)d_in[6];
    const float* mp_w2 = (const float*)d_in[7];  const float* mp_b2 = (const float*)d_in[8];
    const float* bp_w1 = (const float*)d_in[9];  const float* bp_b1 = (const float*)d_in[10];
    const float* bp_w2 = (const float*)d_in[11]; const float* bp_b2 = (const float*)d_in[12];
    const float* env_w1 = (const float*)d_in[13]; const float* env_b1 = (const float*)d_in[14];
    const float* env_w2 = (const float*)d_in[15]; const float* env_b2 = (const float*)d_in[16];
    const float* env_w3 = (const float*)d_in[17]; const float* env_b3 = (const float*)d_in[18];
    const float* task_emb = (const float*)d_in[19];
    const float* tp_w = (const float*)d_in[20]; const float* tp_b = (const float*)d_in[21];
    const float* grid_pos = (const float*)d_in[22];
    const float* dens_w = (const float*)d_in[23]; const float* dens_b = (const float*)d_in[24];
    const float* ln1_w = (const float*)d_in[25]; const float* ln1_b = (const float*)d_in[26];
    const float* wq = (const float*)d_in[27]; const float* bq = (const float*)d_in[28];
    const float* wk = (const float*)d_in[29]; const float* bk = (const float*)d_in[30];
    const float* wv = (const float*)d_in[31]; const float* bv = (const float*)d_in[32];
    const float* wo = (const float*)d_in[33]; const float* bo = (const float*)d_in[34];
    const float* ln2_w = (const float*)d_in[35]; const float* ln2_b = (const float*)d_in[36];
    const float* ff_w1 = (const float*)d_in[37]; const float* ff_b1 = (const float*)d_in[38];
    const float* ff_w2 = (const float*)d_in[39]; const float* ff_b2 = (const float*)d_in[40];
    const float* tfp_w = (const float*)d_in[41]; const float* tfp_b = (const float*)d_in[42];
    const float* head_w = (const float*)d_in[43]; const float* head_b = (const float*)d_in[44];
    float* out = (float*)d_out;

    float* ws = (float*)d_ws;
    size_t off = 0;
    float* src    = ws + off; off += (size_t)B * NS * D;   // 525312
    float* src_xy = ws + off; off += (size_t)B * NS * 2;
    float* dens   = ws + off; off += (size_t)B * KK;
    float* tvec   = ws + off; off += (size_t)B * D;
    float* h1     = ws + off; off += (size_t)B * EC * KK;  // 524288
    float* h2     = ws + off; off += (size_t)B * EC * KK;
    float* grid   = ws + off; off += (size_t)B * KK * D;   // 4.19M
    float* bufA   = ws + off; off += (size_t)B * KK * D;
    float* bufB   = ws + off; off += (size_t)B * KK * D;
    float* kkb    = ws + off; off += (size_t)B * NS * D;
    float* vvb    = ws + off; off += (size_t)B * NS * D;
    (void)ws_size; (void)n_in; (void)in_sizes; (void)out_size;

    const int M = B * KK;       // 16384
    const int Msrc = B * NS;    // 2052

    tok_mlp_k<<<B * N + B, 256, 0, stream>>>(meas_xy, meas_v, bs_xy, mp_w1, mp_b1, mp_w2, mp_b2,
                                             bp_w1, bp_b1, bp_w2, bp_b2, src, src_xy);
    density_k<<<B * 16, 256, 0, stream>>>(meas_xy, dens);
    conv1_k<<<(B * EC * KK) / 256, 256, 0, stream>>>(city, env_w1, env_b1, h1);
    conv2_k<<<(B * EC * KK) / 256, 256, 0, stream>>>(h1, env_w2, env_b2, h2);
    tvec_k<<<B, 256, 0, stream>>>(task_emb, task_id, tp_w, tp_b, tvec);
    grid_init_k<<<M, 256, 0, stream>>>(h2, env_w3, env_b3, grid_pos, tvec, grid);

    for (int l = 0; l < LYR; l++) {
        dens_inject_k<<<M, 256, 0, stream>>>(grid, dens, dens_w + l * D, dens_b + l * D);
        ln_k<<<M, 256, 0, stream>>>(grid, ln1_w + l * D, ln1_b + l * D, bufA);
        // q = hn @ wq + bq
        gemm_k<0, 0><<<dim3(D / 64, M / 64), 256, 0, stream>>>(bufA, wq + (size_t)l * D * D,
                                                               bq + l * D, bufB, M, D, D);
        // k,v = src @ wk/wv + b
        gemm_k<0, 0><<<dim3(D / 64, (Msrc + 63) / 64), 256, 0, stream>>>(src, wk + (size_t)l * D * D,
                                                                         bk + l * D, kkb, Msrc, D, D);
        gemm_k<0, 0><<<dim3(D / 64, (Msrc + 63) / 64), 256, 0, stream>>>(src, wv + (size_t)l * D * D,
                                                                         bv + l * D, vvb, Msrc, D, D);
        attn_k<<<B * NH * 16, 256, 0, stream>>>(bufB, kkb, vvb, src_xy, bufA);
        // grid += attn_out @ wo + bo
        gemm_k<0, 1><<<dim3(D / 64, M / 64), 256, 0, stream>>>(bufA, wo + (size_t)l * D * D,
                                                               bo + l * D, grid, M, D, D);
        // FF: hn2 = LN2(grid); chunked over rows: bufA = gelu(hn2@w1+b1); grid += bufA@w2+b2
        ln_k<<<M, 256, 0, stream>>>(grid, ln2_w + l * D, ln2_b + l * D, bufB);
        for (int c = 0; c < 4; c++) {
            const float* a1 = bufB + (size_t)c * 4096 * D;
            float* gout = grid + (size_t)c * 4096 * D;
            gemm_k<1, 0><<<dim3(DFF / 64, 4096 / 64), 256, 0, stream>>>(
                a1, ff_w1 + (size_t)l * D * DFF, ff_b1 + l * DFF, bufA, 4096, D, DFF);
            gemm_k<0, 1><<<dim3(D / 64, 4096 / 64), 256, 0, stream>>>(
                bufA, ff_w2 + (size_t)l * DFF * D, ff_b2 + l * D, gout, 4096, DFF, D);
        }
    }
    head_k<<<M, 256, 0, stream>>>(grid, task_id, tfp_w, tfp_b, head_w, head_b, out);
}

// Round 2
// 1787.946 us; speedup vs baseline: 1.3416x; 1.3416x over previous
//
#include <hip/hip_runtime.h>
#include <hip/hip_bf16.h>
#include <math.h>

#define D 256
#define NH 8
#define DH 32
#define LYR 2
#define G 64
#define KK 4096
#define T 4
#define EC 32
#define B 4
#define N 512
#define CITY 256
#define DFF 1024
#define NS 513   // N + 1 bs token

typedef short bf16x8 __attribute__((ext_vector_type(8)));
typedef float f32x4 __attribute__((ext_vector_type(4)));

__device__ __forceinline__ float gelu_f(float x) {
    const float c = 0.7978845608028654f; // sqrt(2/pi)
    float x3 = x * x * x;
    return 0.5f * x * (1.f + tanhf(c * (x + 0.044715f * x3)));
}

// round-to-nearest-even f32 -> bf16 bits
__device__ __forceinline__ unsigned short f2bf(float f) {
    unsigned int u = __float_as_uint(f);
    unsigned int r = (u + 0x7FFFu + ((u >> 16) & 1u)) >> 16;
    return (unsigned short)r;
}

// ---------------- token MLPs (meas + bs) -> src, src_xy ----------------
__global__ void tok_mlp_k(const float* __restrict__ meas_xy, const float* __restrict__ meas_v,
                          const float* __restrict__ bs_xy,
                          const float* __restrict__ mp_w1, const float* __restrict__ mp_b1,
                          const float* __restrict__ mp_w2, const float* __restrict__ mp_b2,
                          const float* __restrict__ bp_w1, const float* __restrict__ bp_b1,
                          const float* __restrict__ bp_w2, const float* __restrict__ bp_b2,
                          float* __restrict__ src, float* __restrict__ src_xy) {
    int id = blockIdx.x;
    int d = threadIdx.x;
    __shared__ float hid[D];
    int row;
    const float *w1, *b1, *w2, *b2;
    float x0, x1, x2 = 0.f;
    int nin;
    if (id < B * N) {
        int b = id >> 9, n = id & 511;
        x0 = meas_xy[(b * N + n) * 2 + 0];
        x1 = meas_xy[(b * N + n) * 2 + 1];
        x2 = meas_v[b * N + n];
        w1 = mp_w1; b1 = mp_b1; w2 = mp_w2; b2 = mp_b2; nin = 3;
        row = b * NS + n;
    } else {
        int b = id - B * N;
        x0 = bs_xy[b * 2 + 0];
        x1 = bs_xy[b * 2 + 1];
        w1 = bp_w1; b1 = bp_b1; w2 = bp_w2; b2 = bp_b2; nin = 2;
        row = b * NS + N;
    }
    float h = x0 * w1[d] + x1 * w1[D + d] + b1[d];
    if (nin == 3) h += x2 * w1[2 * D + d];
    hid[d] = gelu_f(h);
    __syncthreads();
    float o = b2[d];
    for (int j = 0; j < D; j++) o += hid[j] * w2[j * D + d];
    src[(size_t)row * D + d] = o;
    if (d == 0) { src_xy[row * 2 + 0] = x0; src_xy[row * 2 + 1] = x1; }
}

// ---------------- gaussian density [B,K] ----------------
__global__ void density_k(const float* __restrict__ meas_xy, float* __restrict__ dens) {
    int b = blockIdx.x >> 4, kc = blockIdx.x & 15;
    int k = kc * 256 + threadIdx.x;
    __shared__ float mx[N], my[N];
    for (int i = threadIdx.x; i < N; i += 256) {
        mx[i] = meas_xy[(b * N + i) * 2 + 0];
        my[i] = meas_xy[(b * N + i) * 2 + 1];
    }
    __syncthreads();
    float gx = ((k & 63) + 0.5f) / 64.f;
    float gy = ((k >> 6) + 0.5f) / 64.f;
    float s = 0.f;
    for (int n = 0; n < N; n++) {
        float dx = gx - mx[n], dy = gy - my[n];
        s += __expf(-(dx * dx + dy * dy) * 78.125f); // 1/(2*0.08^2)
    }
    dens[b * KK + k] = s * (1.f / (float)N);
}

// ---------------- env CNN ----------------
__global__ void conv1_k(const float* __restrict__ city, const float* __restrict__ w,
                        const float* __restrict__ bias, float* __restrict__ h1) {
    int i = blockIdx.x * 256 + threadIdx.x;   // ((b*EC+c)*4096 + y*64 + x)
    int x = i & 63, y = (i >> 6) & 63, c = (i >> 12) & 31, b = i >> 17;
    float s = bias[c];
    for (int ky = 0; ky < 3; ky++) {
        int yy = y + ky - 1;
        if (yy < 0 || yy >= G) continue;
        for (int kx = 0; kx < 3; kx++) {
            int xx = x + kx - 1;
            if (xx < 0 || xx >= G) continue;
            s += city[(b * CITY + yy * 4) * CITY + xx * 4] * w[c * 9 + ky * 3 + kx];
        }
    }
    h1[i] = gelu_f(s);
}

__global__ void conv2_k(const float* __restrict__ h1, const float* __restrict__ w,
                        const float* __restrict__ bias, float* __restrict__ h2) {
    int i = blockIdx.x * 256 + threadIdx.x;
    int x = i & 63, y = (i >> 6) & 63, c = (i >> 12) & 31, b = i >> 17;
    float s = bias[c];
    for (int ci = 0; ci < EC; ci++) {
        const float* hp = h1 + (((size_t)b * EC + ci) << 12);
        const float* wp = w + (c * EC + ci) * 9;
        for (int ky = 0; ky < 3; ky++) {
            int yy = y + ky - 1;
            if (yy < 0 || yy >= G) continue;
            for (int kx = 0; kx < 3; kx++) {
                int xx = x + kx - 1;
                if (xx < 0 || xx >= G) continue;
                s += hp[yy * G + xx] * wp[ky * 3 + kx];
            }
        }
    }
    h2[i] = gelu_f(s);
}

// ---------------- task vector ----------------
__global__ void tvec_k(const float* __restrict__ task_emb, const int* __restrict__ task_id,
                       const float* __restrict__ tp_w, const float* __restrict__ tp_b,
                       float* __restrict__ tvec) {
    int b = blockIdx.x, d = threadIdx.x;
    __shared__ float e[D];
    e[d] = task_emb[task_id[b] * D + d];
    __syncthreads();
    float s = tp_b[d];
    for (int j = 0; j < D; j++) s += e[j] * tp_w[j * D + d];
    tvec[b * D + d] = s;
}

// ---------------- grid init: grid_pos + task_vec + env conv3 ----------------
__global__ void grid_init_k(const float* __restrict__ h2, const float* __restrict__ w3,
                            const float* __restrict__ b3, const float* __restrict__ grid_pos,
                            const float* __restrict__ tvec, float* __restrict__ grid) {
    size_t i = (size_t)blockIdx.x * 256 + threadIdx.x;  // B*K*D
    int d = i & 255;
    size_t bk = i >> 8;
    int k = (int)(bk & 4095), b = (int)(bk >> 12);
    float s = b3[d];
    for (int ci = 0; ci < EC; ci++)
        s += h2[(((size_t)b * EC + ci) << 12) + k] * w3[d * EC + ci];
    grid[i] = s + grid_pos[(size_t)k * D + d] + tvec[b * D + d];
}

// ---------------- density injection (in place) ----------------
__global__ void dens_inject_k(float* __restrict__ grid, const float* __restrict__ dens,
                              const float* __restrict__ dw, const float* __restrict__ db) {
    size_t i = (size_t)blockIdx.x * 256 + threadIdx.x;
    int d = i & 255;
    size_t bk = i >> 8;
    grid[i] += dens[bk] * dw[d] + db[d];
}

// ---------------- layernorm ----------------
__global__ void ln_k(const float* __restrict__ x, const float* __restrict__ w,
                     const float* __restrict__ b, float* __restrict__ y) {
    size_t t = blockIdx.x;
    int d = threadIdx.x;
    float v = x[t * D + d];
    __shared__ float red[D];
    red[d] = v;
    __syncthreads();
    for (int s = 128; s > 0; s >>= 1) { if (d < s) red[d] += red[d + s]; __syncthreads(); }
    float mean = red[0] * (1.f / D);
    __syncthreads();
    float c = v - mean;
    red[d] = c * c;
    __syncthreads();
    for (int s = 128; s > 0; s >>= 1) { if (d < s) red[d] += red[d + s]; __syncthreads(); }
    float var = red[0] * (1.f / D);
    y[t * D + d] = c * rsqrtf(var + 1e-5f) * w[d] + b[d];
}

// ---------------- bf16 MFMA GEMM: C[M,N] = A[M,K] @ W[K,N] + bias ----------------
// 64x64 tile, 256 threads = 4 waves, each wave does 16 rows x 64 cols via
// 4x mfma_f32_16x16x32_bf16 per 32-wide K chunk. f32 accumulate + f32 epilogue.
// A-frag: A[m=lane&15][k=quad*8+j]; B-frag: W[k=quad*8+j][n=lane&15] (from Wt[n][k]).
// C/D: col=lane&15, row=quad*4+reg  [verified layouts per guide m89/m91].
template <int GELU, int ACCUM>
__global__ void gemm_mfma(const float* __restrict__ A, const float* __restrict__ W,
                          const float* __restrict__ bias, float* __restrict__ C,
                          int M, int K, int Nn) {
    __shared__ unsigned short As[64][40];   // stride 40 keeps 16B-aligned rows, breaks pow2 banks
    __shared__ unsigned short Wt[64][40];
    int bn = blockIdx.x * 64, bm = blockIdx.y * 64;
    int tid = threadIdx.x;
    int wave = tid >> 6, lane = tid & 63;
    int q = lane >> 4, lr = lane & 15;
    f32x4 acc[4];
    #pragma unroll
    for (int j = 0; j < 4; j++) { acc[j][0] = 0.f; acc[j][1] = 0.f; acc[j][2] = 0.f; acc[j][3] = 0.f; }

    for (int k0 = 0; k0 < K; k0 += 32) {
        // stage A tile [64 rows x 32 k] -> bf16
        #pragma unroll
        for (int t = 0; t < 2; t++) {
            int idx = tid * 2 + t;              // 0..511 float4s
            int r = idx >> 3, c4 = (idx & 7) * 4;
            int gr = bm + r;
            float4 v;
            if (gr < M) v = *(const float4*)(A + (size_t)gr * K + k0 + c4);
            else { v.x = 0.f; v.y = 0.f; v.z = 0.f; v.w = 0.f; }
            As[r][c4 + 0] = f2bf(v.x); As[r][c4 + 1] = f2bf(v.y);
            As[r][c4 + 2] = f2bf(v.z); As[r][c4 + 3] = f2bf(v.w);
        }
        // stage W tile [32 k x 64 n], transposed into Wt[n][k]
        #pragma unroll
        for (int t = 0; t < 2; t++) {
            int idx = tid * 2 + t;              // 0..511 float4s
            int kr = idx >> 4, c4 = (idx & 15) * 4;
            float4 v = *(const float4*)(W + (size_t)(k0 + kr) * Nn + bn + c4);
            Wt[c4 + 0][kr] = f2bf(v.x); Wt[c4 + 1][kr] = f2bf(v.y);
            Wt[c4 + 2][kr] = f2bf(v.z); Wt[c4 + 3][kr] = f2bf(v.w);
        }
        __syncthreads();
        bf16x8 af = *(const bf16x8*)&As[wave * 16 + lr][q * 8];
        #pragma unroll
        for (int j = 0; j < 4; j++) {
            bf16x8 bf = *(const bf16x8*)&Wt[j * 16 + lr][q * 8];
            acc[j] = __builtin_amdgcn_mfma_f32_16x16x32_bf16(af, bf, acc[j], 0, 0, 0);
        }
        __syncthreads();
    }
    #pragma unroll
    for (int j = 0; j < 4; j++) {
        int gc = bn + j * 16 + lr;
        float bv = bias[gc];
        #pragma unroll
        for (int r = 0; r < 4; r++) {
            int gr = bm + wave * 16 + q * 4 + r;
            if (gr < M) {
                float v = acc[j][r] + bv;
                if (GELU) v = gelu_f(v);
                if (ACCUM) C[(size_t)gr * Nn + gc] += v;
                else C[(size_t)gr * Nn + gc] = v;
            }
        }
    }
}

// ---------------- task-indexed MFMA GEMM (tfp weight bank) + GELU ----------------
__global__ void gemm_task_mfma(const float* __restrict__ A, const float* __restrict__ tfp_w,
                               const float* __restrict__ tfp_b, const int* __restrict__ task_id,
                               float* __restrict__ C) {
    __shared__ unsigned short As[64][40];
    __shared__ unsigned short Wt[64][40];
    int bn = blockIdx.x * 64, bm = blockIdx.y * 64;
    int tsk = task_id[blockIdx.y >> 6];         // 4096 rows per sample, 64 rows per block
    const float* W = tfp_w + (size_t)tsk * D * D;
    const float* bias = tfp_b + tsk * D;
    int tid = threadIdx.x;
    int wave = tid >> 6, lane = tid & 63;
    int q = lane >> 4, lr = lane & 15;
    f32x4 acc[4];
    #pragma unroll
    for (int j = 0; j < 4; j++) { acc[j][0] = 0.f; acc[j][1] = 0.f; acc[j][2] = 0.f; acc[j][3] = 0.f; }

    for (int k0 = 0; k0 < D; k0 += 32) {
        #pragma unroll
        for (int t = 0; t < 2; t++) {
            int idx = tid * 2 + t;
            int r = idx >> 3, c4 = (idx & 7) * 4;
            float4 v = *(const float4*)(A + (size_t)(bm + r) * D + k0 + c4);
            As[r][c4 + 0] = f2bf(v.x); As[r][c4 + 1] = f2bf(v.y);
            As[r][c4 + 2] = f2bf(v.z); As[r][c4 + 3] = f2bf(v.w);
        }
        #pragma unroll
        for (int t = 0; t < 2; t++) {
            int idx = tid * 2 + t;
            int kr = idx >> 4, c4 = (idx & 15) * 4;
            float4 v = *(const float4*)(W + (size_t)(k0 + kr) * D + bn + c4);
            Wt[c4 + 0][kr] = f2bf(v.x); Wt[c4 + 1][kr] = f2bf(v.y);
            Wt[c4 + 2][kr] = f2bf(v.z); Wt[c4 + 3][kr] = f2bf(v.w);
        }
        __syncthreads();
        bf16x8 af = *(const bf16x8*)&As[wave * 16 + lr][q * 8];
        #pragma unroll
        for (int j = 0; j < 4; j++) {
            bf16x8 bf = *(const bf16x8*)&Wt[j * 16 + lr][q * 8];
            acc[j] = __builtin_amdgcn_mfma_f32_16x16x32_bf16(af, bf, acc[j], 0, 0, 0);
        }
        __syncthreads();
    }
    #pragma unroll
    for (int j = 0; j < 4; j++) {
        int gc = bn + j * 16 + lr;
        float bv = bias[gc];
        #pragma unroll
        for (int r = 0; r < 4; r++) {
            int gr = bm + wave * 16 + q * 4 + r;
            C[(size_t)gr * D + gc] = gelu_f(acc[j][r] + bv);
        }
    }
}

// ---------------- head reduction: out[row] = dot(X[row], head_w) + head_b ----------------
__global__ void head_red_k(const float* __restrict__ X, const float* __restrict__ head_w,
                           const float* __restrict__ head_b, float* __restrict__ out) {
    int row = blockIdx.x * 4 + (threadIdx.x >> 6);
    int lane = threadIdx.x & 63;
    float4 x = *(const float4*)(X + (size_t)row * D + lane * 4);
    float4 w = *(const float4*)(head_w + lane * 4);
    float s = x.x * w.x + x.y * w.y + x.z * w.z + x.w * w.w;
    #pragma unroll
    for (int off = 32; off > 0; off >>= 1) s += __shfl_down(s, off);
    if (lane == 0) out[row] = s + head_b[0];
}

// ---------------- flash-style cross attention with distance bias ----------------
__global__ void attn_k(const float* __restrict__ q, const float* __restrict__ kkb,
                       const float* __restrict__ vvb, const float* __restrict__ sxy,
                       float* __restrict__ out) {
    int bid = blockIdx.x;                 // ((b*NH + h)*16 + kc)
    int kc = bid & 15, h = (bid >> 4) & 7, b = bid >> 7;
    int tid = threadIdx.x;
    int k = kc * 256 + tid;
    float gx = ((k & 63) + 0.5f) / 64.f;
    float gy = ((k >> 6) + 0.5f) / 64.f;
    float qv[DH];
    const float* qp = q + ((size_t)(b * KK + k)) * D + h * DH;
    #pragma unroll
    for (int j = 0; j < DH; j++) qv[j] = qp[j];
    float m = -1e30f, l = 0.f;
    float acc[DH] = {};
    __shared__ float ks[128][DH];
    __shared__ float vs[128][DH];
    __shared__ float sx[128], sy[128];
    const float inv_sqrt = 0.17677669529663687f; // 1/sqrt(32)
    for (int n0 = 0; n0 < NS; n0 += 128) {
        int cnt = min(128, NS - n0);
        __syncthreads();
        for (int i = tid; i < cnt * DH; i += 256) {
            int n = i >> 5, j = i & 31;
            size_t base = ((size_t)(b * NS + n0 + n)) * D + h * DH + j;
            ks[n][j] = kkb[base];
            vs[n][j] = vvb[base];
        }
        for (int i = tid; i < cnt; i += 256) {
            sx[i] = sxy[(b * NS + n0 + i) * 2 + 0];
            sy[i] = sxy[(b * NS + n0 + i) * 2 + 1];
        }
        __syncthreads();
        for (int n = 0; n < cnt; n++) {
            float s = 0.f;
            #pragma unroll
            for (int j = 0; j < DH; j++) s += qv[j] * ks[n][j];
            float dx = gx - sx[n], dy = gy - sy[n];
            s = s * inv_sqrt - sqrtf(dx * dx + dy * dy);
            float mn = fmaxf(m, s);
            float scale = __expf(m - mn);
            float p = __expf(s - mn);
            l = l * scale + p;
            #pragma unroll
            for (int j = 0; j < DH; j++) acc[j] = acc[j] * scale + p * vs[n][j];
            m = mn;
        }
    }
    float inv = 1.f / l;
    float* op = out + ((size_t)(b * KK + k)) * D + h * DH;
    #pragma unroll
    for (int j = 0; j < DH; j++) op[j] = acc[j] * inv;
}

extern "C" void kernel_launch(void* const* d_in, const int* in_sizes, int n_in,
                              void* d_out, int out_size, void* d_ws, size_t ws_size,
                              hipStream_t stream) {
    const float* meas_xy = (const float*)d_in[0];
    const float* meas_v  = (const float*)d_in[1];
    const float* bs_xy   = (const float*)d_in[2];
    const int*   task_id = (const int*)d_in[3];
    const float* city    = (const float*)d_in[4];
    const float* mp_w1 = (const float*)d_in[5];  const float* mp_b1 = (const float*)d_in[6];
    const float* mp_w2 = (const float*)d_in[7];  const float* mp_b2 = (const float*)d_in[8];
    const float* bp_w1 = (const float*)d_in[9];  const float* bp_b1 = (const float*)d_in[10];
    const float* bp_w2 = (const float*)d_in[11]; const float* bp_b2 = (const float*)d_in[12];
    const float* env_w1 = (const float*)d_in[13]; const float* env_b1 = (const float*)d_in[14];
    const float* env_w2 = (const float*)d_in[15]; const float* env_b2 = (const float*)d_in[16];
    const float* env_w3 = (const float*)d_in[17]; const float* env_b3 = (const float*)d_in[18];
    const float* task_emb = (const float*)d_in[19];
    const float* tp_w = (const float*)d_in[20]; const float* tp_b = (const float*)d_in[21];
    const float* grid_pos = (const float*)d_in[22];
    const float* dens_w = (const float*)d_in[23]; const float* dens_b = (const float*)d_in[24];
    const float* ln1_w = (const float*)d_in[25]; const float* ln1_b = (const float*)d_in[26];
    const float* wq = (const float*)d_in[27]; const float* bq = (const float*)d_in[28];
    const float* wk = (const float*)d_in[29]; const float* bk = (const float*)d_in[30];
    const float* wv = (const float*)d_in[31]; const float* bv = (const float*)d_in[32];
    const float* wo = (const float*)d_in[33]; const float* bo = (const float*)d_in[34];
    const float* ln2_w = (const float*)d_in[35]; const float* ln2_b = (const float*)d_in[36];
    const float* ff_w1 = (const float*)d_in[37]; const float* ff_b1 = (const float*)d_in[38];
    const float* ff_w2 = (const float*)d_in[39]; const float* ff_b2 = (const float*)d_in[40];
    const float* tfp_w = (const float*)d_in[41]; const float* tfp_b = (const float*)d_in[42];
    const float* head_w = (const float*)d_in[43]; const float* head_b = (const float*)d_in[44];
    float* out = (float*)d_out;

    float* ws = (float*)d_ws;
    size_t off = 0;
    float* src    = ws + off; off += (size_t)B * NS * D;   // 525312
    float* src_xy = ws + off; off += (size_t)B * NS * 2;
    float* dens   = ws + off; off += (size_t)B * KK;
    float* tvec   = ws + off; off += (size_t)B * D;
    float* h1     = ws + off; off += (size_t)B * EC * KK;  // 524288
    float* h2     = ws + off; off += (size_t)B * EC * KK;
    float* grid   = ws + off; off += (size_t)B * KK * D;   // 4.19M
    float* bufA   = ws + off; off += (size_t)B * KK * D;
    float* bufB   = ws + off; off += (size_t)B * KK * D;
    float* kkb    = ws + off; off += (size_t)B * NS * D;
    float* vvb    = ws + off; off += (size_t)B * NS * D;
    (void)ws_size; (void)n_in; (void)in_sizes; (void)out_size;

    const int M = B * KK;       // 16384
    const int Msrc = B * NS;    // 2052

    tok_mlp_k<<<B * N + B, 256, 0, stream>>>(meas_xy, meas_v, bs_xy, mp_w1, mp_b1, mp_w2, mp_b2,
                                             bp_w1, bp_b1, bp_w2, bp_b2, src, src_xy);
    density_k<<<B * 16, 256, 0, stream>>>(meas_xy, dens);
    conv1_k<<<(B * EC * KK) / 256, 256, 0, stream>>>(city, env_w1, env_b1, h1);
    conv2_k<<<(B * EC * KK) / 256, 256, 0, stream>>>(h1, env_w2, env_b2, h2);
    tvec_k<<<B, 256, 0, stream>>>(task_emb, task_id, tp_w, tp_b, tvec);
    grid_init_k<<<M, 256, 0, stream>>>(h2, env_w3, env_b3, grid_pos, tvec, grid);

    for (int l = 0; l < LYR; l++) {
        dens_inject_k<<<M, 256, 0, stream>>>(grid, dens, dens_w + l * D, dens_b + l * D);
        ln_k<<<M, 256, 0, stream>>>(grid, ln1_w + l * D, ln1_b + l * D, bufA);
        // q = hn @ wq + bq
        gemm_mfma<0, 0><<<dim3(D / 64, M / 64), 256, 0, stream>>>(bufA, wq + (size_t)l * D * D,
                                                                  bq + l * D, bufB, M, D, D);
        // k,v = src @ wk/wv + b
        gemm_mfma<0, 0><<<dim3(D / 64, (Msrc + 63) / 64), 256, 0, stream>>>(
            src, wk + (size_t)l * D * D, bk + l * D, kkb, Msrc, D, D);
        gemm_mfma<0, 0><<<dim3(D / 64, (Msrc + 63) / 64), 256, 0, stream>>>(
            src, wv + (size_t)l * D * D, bv + l * D, vvb, Msrc, D, D);
        attn_k<<<B * NH * 16, 256, 0, stream>>>(bufB, kkb, vvb, src_xy, bufA);
        // grid += attn_out @ wo + bo
        gemm_mfma<0, 1><<<dim3(D / 64, M / 64), 256, 0, stream>>>(bufA, wo + (size_t)l * D * D,
                                                                  bo + l * D, grid, M, D, D);
        // FF: hn2 = LN2(grid); chunked over rows: bufA = gelu(hn2@w1+b1); grid += bufA@w2+b2
        ln_k<<<M, 256, 0, stream>>>(grid, ln2_w + l * D, ln2_b + l * D, bufB);
        for (int c = 0; c < 4; c++) {
            const float* a1 = bufB + (size_t)c * 4096 * D;
            float* gout = grid + (size_t)c * 4096 * D;
            gemm_mfma<1, 0><<<dim3(DFF / 64, 4096 / 64), 256, 0, stream>>>(
                a1, ff_w1 + (size_t)l * D * DFF, ff_b1 + l * DFF, bufA, 4096, D, DFF);
            gemm_mfma<0, 1><<<dim3(D / 64, 4096 / 64), 256, 0, stream>>>(
                bufA, ff_w2 + (size_t)l * DFF * D, ff_b2 + l * D, gout, 4096, DFF, D);
        }
    }
    // head: tf = gelu(grid @ tfp_w[task] + tfp_b[task]); out = tf @ head_w + head_b
    gemm_task_mfma<<<dim3(D / 64, M / 64), 256, 0, stream>>>(grid, tfp_w, tfp_b, task_id, bufA);
    head_red_k<<<M / 4, 256, 0, stream>>>(bufA, head_w, head_b, out);
}

// Round 3
// 1277.414 us; speedup vs baseline: 1.8777x; 1.3997x over previous
//
#include <hip/hip_runtime.h>
#include <hip/hip_bf16.h>
#include <math.h>

#define D 256
#define NH 8
#define DH 32
#define LYR 2
#define G 64
#define KK 4096
#define T 4
#define EC 32
#define B 4
#define N 512
#define CITY 256
#define DFF 1024
#define NS 513   // N + 1 bs token
#define NSP 544  // 17 * 32 padded token count for attention chunks

typedef short bf16x8 __attribute__((ext_vector_type(8)));
typedef float f32x4 __attribute__((ext_vector_type(4)));

__device__ __forceinline__ float gelu_f(float x) {
    const float c = 0.7978845608028654f; // sqrt(2/pi)
    float x3 = x * x * x;
    return 0.5f * x * (1.f + tanhf(c * (x + 0.044715f * x3)));
}

// round-to-nearest-even f32 -> bf16 bits
__device__ __forceinline__ unsigned short f2bf(float f) {
    unsigned int u = __float_as_uint(f);
    unsigned int r = (u + 0x7FFFu + ((u >> 16) & 1u)) >> 16;
    return (unsigned short)r;
}

// ---------------- token MLPs (meas + bs) -> src, src_xy ----------------
__global__ void tok_mlp_k(const float* __restrict__ meas_xy, const float* __restrict__ meas_v,
                          const float* __restrict__ bs_xy,
                          const float* __restrict__ mp_w1, const float* __restrict__ mp_b1,
                          const float* __restrict__ mp_w2, const float* __restrict__ mp_b2,
                          const float* __restrict__ bp_w1, const float* __restrict__ bp_b1,
                          const float* __restrict__ bp_w2, const float* __restrict__ bp_b2,
                          float* __restrict__ src, float* __restrict__ src_xy) {
    int id = blockIdx.x;
    int d = threadIdx.x;
    __shared__ float hid[D];
    int row;
    const float *w1, *b1, *w2, *b2;
    float x0, x1, x2 = 0.f;
    int nin;
    if (id < B * N) {
        int b = id >> 9, n = id & 511;
        x0 = meas_xy[(b * N + n) * 2 + 0];
        x1 = meas_xy[(b * N + n) * 2 + 1];
        x2 = meas_v[b * N + n];
        w1 = mp_w1; b1 = mp_b1; w2 = mp_w2; b2 = mp_b2; nin = 3;
        row = b * NS + n;
    } else {
        int b = id - B * N;
        x0 = bs_xy[b * 2 + 0];
        x1 = bs_xy[b * 2 + 1];
        w1 = bp_w1; b1 = bp_b1; w2 = bp_w2; b2 = bp_b2; nin = 2;
        row = b * NS + N;
    }
    float h = x0 * w1[d] + x1 * w1[D + d] + b1[d];
    if (nin == 3) h += x2 * w1[2 * D + d];
    hid[d] = gelu_f(h);
    __syncthreads();
    float o = b2[d];
    for (int j = 0; j < D; j++) o += hid[j] * w2[j * D + d];
    src[(size_t)row * D + d] = o;
    if (d == 0) { src_xy[row * 2 + 0] = x0; src_xy[row * 2 + 1] = x1; }
}

// ---------------- gaussian density [B,K] ----------------
__global__ void density_k(const float* __restrict__ meas_xy, float* __restrict__ dens) {
    int b = blockIdx.x >> 4, kc = blockIdx.x & 15;
    int k = kc * 256 + threadIdx.x;
    __shared__ float mx[N], my[N];
    for (int i = threadIdx.x; i < N; i += 256) {
        mx[i] = meas_xy[(b * N + i) * 2 + 0];
        my[i] = meas_xy[(b * N + i) * 2 + 1];
    }
    __syncthreads();
    float gx = ((k & 63) + 0.5f) / 64.f;
    float gy = ((k >> 6) + 0.5f) / 64.f;
    float s = 0.f;
    for (int n = 0; n < N; n++) {
        float dx = gx - mx[n], dy = gy - my[n];
        s += __expf(-(dx * dx + dy * dy) * 78.125f); // 1/(2*0.08^2)
    }
    dens[b * KK + k] = s * (1.f / (float)N);
}

// ---------------- env CNN ----------------
__global__ void conv1_k(const float* __restrict__ city, const float* __restrict__ w,
                        const float* __restrict__ bias, float* __restrict__ h1) {
    int i = blockIdx.x * 256 + threadIdx.x;   // ((b*EC+c)*4096 + y*64 + x)
    int x = i & 63, y = (i >> 6) & 63, c = (i >> 12) & 31, b = i >> 17;
    float s = bias[c];
    for (int ky = 0; ky < 3; ky++) {
        int yy = y + ky - 1;
        if (yy < 0 || yy >= G) continue;
        for (int kx = 0; kx < 3; kx++) {
            int xx = x + kx - 1;
            if (xx < 0 || xx >= G) continue;
            s += city[(b * CITY + yy * 4) * CITY + xx * 4] * w[c * 9 + ky * 3 + kx];
        }
    }
    h1[i] = gelu_f(s);
}

__global__ void conv2_k(const float* __restrict__ h1, const float* __restrict__ w,
                        const float* __restrict__ bias, float* __restrict__ h2) {
    int i = blockIdx.x * 256 + threadIdx.x;
    int x = i & 63, y = (i >> 6) & 63, c = (i >> 12) & 31, b = i >> 17;
    float s = bias[c];
    for (int ci = 0; ci < EC; ci++) {
        const float* hp = h1 + (((size_t)b * EC + ci) << 12);
        const float* wp = w + (c * EC + ci) * 9;
        for (int ky = 0; ky < 3; ky++) {
            int yy = y + ky - 1;
            if (yy < 0 || yy >= G) continue;
            for (int kx = 0; kx < 3; kx++) {
                int xx = x + kx - 1;
                if (xx < 0 || xx >= G) continue;
                s += hp[yy * G + xx] * wp[ky * 3 + kx];
            }
        }
    }
    h2[i] = gelu_f(s);
}

// ---------------- task vector ----------------
__global__ void tvec_k(const float* __restrict__ task_emb, const int* __restrict__ task_id,
                       const float* __restrict__ tp_w, const float* __restrict__ tp_b,
                       float* __restrict__ tvec) {
    int b = blockIdx.x, d = threadIdx.x;
    __shared__ float e[D];
    e[d] = task_emb[task_id[b] * D + d];
    __syncthreads();
    float s = tp_b[d];
    for (int j = 0; j < D; j++) s += e[j] * tp_w[j * D + d];
    tvec[b * D + d] = s;
}

// ---------------- grid init: grid_pos + task_vec + env conv3 ----------------
__global__ void grid_init_k(const float* __restrict__ h2, const float* __restrict__ w3,
                            const float* __restrict__ b3, const float* __restrict__ grid_pos,
                            const float* __restrict__ tvec, float* __restrict__ grid) {
    size_t i = (size_t)blockIdx.x * 256 + threadIdx.x;  // B*K*D
    int d = i & 255;
    size_t bk = i >> 8;
    int k = (int)(bk & 4095), b = (int)(bk >> 12);
    float s = b3[d];
    for (int ci = 0; ci < EC; ci++)
        s += h2[(((size_t)b * EC + ci) << 12) + k] * w3[d * EC + ci];
    grid[i] = s + grid_pos[(size_t)k * D + d] + tvec[b * D + d];
}

// ---------------- density injection (in place) ----------------
__global__ void dens_inject_k(float* __restrict__ grid, const float* __restrict__ dens,
                              const float* __restrict__ dw, const float* __restrict__ db) {
    size_t i = (size_t)blockIdx.x * 256 + threadIdx.x;
    int d = i & 255;
    size_t bk = i >> 8;
    grid[i] += dens[bk] * dw[d] + db[d];
}

// ---------------- layernorm ----------------
__global__ void ln_k(const float* __restrict__ x, const float* __restrict__ w,
                     const float* __restrict__ b, float* __restrict__ y) {
    size_t t = blockIdx.x;
    int d = threadIdx.x;
    float v = x[t * D + d];
    __shared__ float red[D];
    red[d] = v;
    __syncthreads();
    for (int s = 128; s > 0; s >>= 1) { if (d < s) red[d] += red[d + s]; __syncthreads(); }
    float mean = red[0] * (1.f / D);
    __syncthreads();
    float c = v - mean;
    red[d] = c * c;
    __syncthreads();
    for (int s = 128; s > 0; s >>= 1) { if (d < s) red[d] += red[d + s]; __syncthreads(); }
    float var = red[0] * (1.f / D);
    y[t * D + d] = c * rsqrtf(var + 1e-5f) * w[d] + b[d];
}

// ---------------- bf16 MFMA GEMM: C[M,N] = A[M,K] @ W[K,N] + bias ----------------
// 64x64 tile, 256 threads = 4 waves. OBF=1 stores bf16 output (for Q/K/V).
template <int GELU, int ACCUM, int OBF>
__global__ void gemm_mfma(const float* __restrict__ A, const float* __restrict__ W,
                          const float* __restrict__ bias, void* __restrict__ Cv,
                          int M, int K, int Nn) {
    __shared__ unsigned short As[64][40];
    __shared__ unsigned short Wt[64][40];
    int bn = blockIdx.x * 64, bm = blockIdx.y * 64;
    int tid = threadIdx.x;
    int wave = tid >> 6, lane = tid & 63;
    int q = lane >> 4, lr = lane & 15;
    f32x4 acc[4];
    #pragma unroll
    for (int j = 0; j < 4; j++) { acc[j][0] = 0.f; acc[j][1] = 0.f; acc[j][2] = 0.f; acc[j][3] = 0.f; }

    for (int k0 = 0; k0 < K; k0 += 32) {
        #pragma unroll
        for (int t = 0; t < 2; t++) {
            int idx = tid * 2 + t;
            int r = idx >> 3, c4 = (idx & 7) * 4;
            int gr = bm + r;
            float4 v;
            if (gr < M) v = *(const float4*)(A + (size_t)gr * K + k0 + c4);
            else { v.x = 0.f; v.y = 0.f; v.z = 0.f; v.w = 0.f; }
            As[r][c4 + 0] = f2bf(v.x); As[r][c4 + 1] = f2bf(v.y);
            As[r][c4 + 2] = f2bf(v.z); As[r][c4 + 3] = f2bf(v.w);
        }
        #pragma unroll
        for (int t = 0; t < 2; t++) {
            int idx = tid * 2 + t;
            int kr = idx >> 4, c4 = (idx & 15) * 4;
            float4 v = *(const float4*)(W + (size_t)(k0 + kr) * Nn + bn + c4);
            Wt[c4 + 0][kr] = f2bf(v.x); Wt[c4 + 1][kr] = f2bf(v.y);
            Wt[c4 + 2][kr] = f2bf(v.z); Wt[c4 + 3][kr] = f2bf(v.w);
        }
        __syncthreads();
        bf16x8 af = *(const bf16x8*)&As[wave * 16 + lr][q * 8];
        #pragma unroll
        for (int j = 0; j < 4; j++) {
            bf16x8 bf = *(const bf16x8*)&Wt[j * 16 + lr][q * 8];
            acc[j] = __builtin_amdgcn_mfma_f32_16x16x32_bf16(af, bf, acc[j], 0, 0, 0);
        }
        __syncthreads();
    }
    #pragma unroll
    for (int j = 0; j < 4; j++) {
        int gc = bn + j * 16 + lr;
        float bv = bias[gc];
        #pragma unroll
        for (int r = 0; r < 4; r++) {
            int gr = bm + wave * 16 + q * 4 + r;
            if (gr < M) {
                float v = acc[j][r] + bv;
                if (GELU) v = gelu_f(v);
                if (OBF) {
                    ((unsigned short*)Cv)[(size_t)gr * Nn + gc] = f2bf(v);
                } else if (ACCUM) {
                    ((float*)Cv)[(size_t)gr * Nn + gc] += v;
                } else {
                    ((float*)Cv)[(size_t)gr * Nn + gc] = v;
                }
            }
        }
    }
}

// ---------------- task-indexed MFMA GEMM (tfp weight bank) + GELU ----------------
__global__ void gemm_task_mfma(const float* __restrict__ A, const float* __restrict__ tfp_w,
                               const float* __restrict__ tfp_b, const int* __restrict__ task_id,
                               float* __restrict__ C) {
    __shared__ unsigned short As[64][40];
    __shared__ unsigned short Wt[64][40];
    int bn = blockIdx.x * 64, bm = blockIdx.y * 64;
    int tsk = task_id[blockIdx.y >> 6];
    const float* W = tfp_w + (size_t)tsk * D * D;
    const float* bias = tfp_b + tsk * D;
    int tid = threadIdx.x;
    int wave = tid >> 6, lane = tid & 63;
    int q = lane >> 4, lr = lane & 15;
    f32x4 acc[4];
    #pragma unroll
    for (int j = 0; j < 4; j++) { acc[j][0] = 0.f; acc[j][1] = 0.f; acc[j][2] = 0.f; acc[j][3] = 0.f; }

    for (int k0 = 0; k0 < D; k0 += 32) {
        #pragma unroll
        for (int t = 0; t < 2; t++) {
            int idx = tid * 2 + t;
            int r = idx >> 3, c4 = (idx & 7) * 4;
            float4 v = *(const float4*)(A + (size_t)(bm + r) * D + k0 + c4);
            As[r][c4 + 0] = f2bf(v.x); As[r][c4 + 1] = f2bf(v.y);
            As[r][c4 + 2] = f2bf(v.z); As[r][c4 + 3] = f2bf(v.w);
        }
        #pragma unroll
        for (int t = 0; t < 2; t++) {
            int idx = tid * 2 + t;
            int kr = idx >> 4, c4 = (idx & 15) * 4;
            float4 v = *(const float4*)(W + (size_t)(k0 + kr) * D + bn + c4);
            Wt[c4 + 0][kr] = f2bf(v.x); Wt[c4 + 1][kr] = f2bf(v.y);
            Wt[c4 + 2][kr] = f2bf(v.z); Wt[c4 + 3][kr] = f2bf(v.w);
        }
        __syncthreads();
        bf16x8 af = *(const bf16x8*)&As[wave * 16 + lr][q * 8];
        #pragma unroll
        for (int j = 0; j < 4; j++) {
            bf16x8 bf = *(const bf16x8*)&Wt[j * 16 + lr][q * 8];
            acc[j] = __builtin_amdgcn_mfma_f32_16x16x32_bf16(af, bf, acc[j], 0, 0, 0);
        }
        __syncthreads();
    }
    #pragma unroll
    for (int j = 0; j < 4; j++) {
        int gc = bn + j * 16 + lr;
        float bv = bias[gc];
        #pragma unroll
        for (int r = 0; r < 4; r++) {
            int gr = bm + wave * 16 + q * 4 + r;
            C[(size_t)gr * D + gc] = gelu_f(acc[j][r] + bv);
        }
    }
}

// ---------------- head reduction: out[row] = dot(X[row], head_w) + head_b ----------------
__global__ void head_red_k(const float* __restrict__ X, const float* __restrict__ head_w,
                           const float* __restrict__ head_b, float* __restrict__ out) {
    int row = blockIdx.x * 4 + (threadIdx.x >> 6);
    int lane = threadIdx.x & 63;
    float4 x = *(const float4*)(X + (size_t)row * D + lane * 4);
    float4 w = *(const float4*)(head_w + lane * 4);
    float s = x.x * w.x + x.y * w.y + x.z * w.z + x.w * w.w;
    #pragma unroll
    for (int off = 32; off > 0; off >>= 1) s += __shfl_down(s, off);
    if (lane == 0) out[row] = s + head_b[0];
}

// ---------------- MFMA flash cross-attention with distance bias ----------------
// Block = 4 waves = one (b, h, 64-query tile); wave owns 16 q-rows.
// 17 chunks of 32 tokens; QK^T and PV via mfma_f32_16x16x32_bf16.
// Layouts (guide-verified): A[m=lane&15][k=quad*8+j]; B[k=quad*8+j][n=lane&15];
// C/D col=lane&15, row=quad*4+reg. Per-row softmax state is quad-uniform.
__global__ __launch_bounds__(256) void attn_mfma(
    const unsigned short* __restrict__ qb,   // [B*KK][D] bf16
    const unsigned short* __restrict__ kb,   // [B*NS][D] bf16 (reads past NS are masked)
    const unsigned short* __restrict__ vb,   // [B*NS][D] bf16
    const float* __restrict__ sxy,           // [B*NS][2]
    float* __restrict__ out)                 // [B*KK][D] f32
{
    int bid = blockIdx.x;                    // b*512 + h*64 + qt
    int qt = bid & 63, h = (bid >> 6) & 7, b = bid >> 9;
    int tid = threadIdx.x, wave = tid >> 6, lane = tid & 63;
    int q4 = lane >> 4, lr = lane & 15;

    __shared__ unsigned short Vt[32][NSP + 8];   // [dh][token], stride 552 (16B-mult, 2-way banks)
    __shared__ float sxs[NSP], sys[NSP];
    __shared__ unsigned short Pw[4][16][40];     // per-wave P transpose buffer

    // stage V transposed (all 17 chunks) + src_xy
    for (int c = 0; c < 17; c++) {
        int tok = c * 32 + (tid >> 3);
        int dh0 = (tid & 7) * 4;
        const unsigned short* vp = vb + ((size_t)(b * NS + tok)) * D + h * DH + dh0;
        ushort4 vv = *(const ushort4*)vp;
        Vt[dh0 + 0][tok] = vv.x; Vt[dh0 + 1][tok] = vv.y;
        Vt[dh0 + 2][tok] = vv.z; Vt[dh0 + 3][tok] = vv.w;
    }
    for (int i = tid; i < NSP; i += 256) {
        sxs[i] = sxy[((size_t)b * NS + i) * 2 + 0];
        sys[i] = sxy[((size_t)b * NS + i) * 2 + 1];
    }
    __syncthreads();

    int kbase = qt * 64 + wave * 16;
    bf16x8 qf = *(const bf16x8*)(qb + ((size_t)(b * KK + kbase + lr)) * D + h * DH + q4 * 8);

    float gxr[4], gyr[4];
    #pragma unroll
    for (int r = 0; r < 4; r++) {
        int kidx = kbase + q4 * 4 + r;
        gxr[r] = ((kidx & 63) + 0.5f) * (1.f / 64.f);
        gyr[r] = (((kidx >> 6) & 63) + 0.5f) * (1.f / 64.f);
    }

    float m[4], l[4];
    f32x4 o0 = {0.f, 0.f, 0.f, 0.f}, o1 = {0.f, 0.f, 0.f, 0.f};
    #pragma unroll
    for (int r = 0; r < 4; r++) { m[r] = -1e30f; l[r] = 0.f; }
    const float isq = 0.17677669529663687f;  // 1/sqrt(32)

    for (int c = 0; c < 17; c++) {
        int n0 = c * 32;
        const unsigned short* kp = kb + ((size_t)(b * NS + n0 + lr)) * D + h * DH + q4 * 8;
        bf16x8 kf0 = *(const bf16x8*)kp;
        bf16x8 kf1 = *(const bf16x8*)(kp + (size_t)16 * D);
        f32x4 s0 = {0.f, 0.f, 0.f, 0.f}, s1 = {0.f, 0.f, 0.f, 0.f};
        s0 = __builtin_amdgcn_mfma_f32_16x16x32_bf16(qf, kf0, s0, 0, 0, 0);
        s1 = __builtin_amdgcn_mfma_f32_16x16x32_bf16(qf, kf1, s1, 0, 0, 0);

        int t0 = n0 + lr, t1 = n0 + 16 + lr;
        float sx0 = sxs[t0], sy0 = sys[t0], sx1 = sxs[t1], sy1 = sys[t1];
        bool v0 = (t0 < NS), v1 = (t1 < NS);
        float sc0[4], sc1[4], alpha[4];
        #pragma unroll
        for (int r = 0; r < 4; r++) {
            float dx = gxr[r] - sx0, dy = gyr[r] - sy0;
            sc0[r] = v0 ? (s0[r] * isq - sqrtf(dx * dx + dy * dy)) : -1e30f;
            dx = gxr[r] - sx1; dy = gyr[r] - sy1;
            sc1[r] = v1 ? (s1[r] * isq - sqrtf(dx * dx + dy * dy)) : -1e30f;
        }
        #pragma unroll
        for (int r = 0; r < 4; r++) {
            float mx = fmaxf(sc0[r], sc1[r]);
            mx = fmaxf(mx, __shfl_xor(mx, 1));
            mx = fmaxf(mx, __shfl_xor(mx, 2));
            mx = fmaxf(mx, __shfl_xor(mx, 4));
            mx = fmaxf(mx, __shfl_xor(mx, 8));
            float mn = fmaxf(m[r], mx);
            alpha[r] = __expf(m[r] - mn);
            m[r] = mn;
            sc0[r] = __expf(sc0[r] - mn);
            sc1[r] = __expf(sc1[r] - mn);
            float sum = sc0[r] + sc1[r];
            sum += __shfl_xor(sum, 1);
            sum += __shfl_xor(sum, 2);
            sum += __shfl_xor(sum, 4);
            sum += __shfl_xor(sum, 8);
            l[r] = l[r] * alpha[r] + sum;
            o0[r] *= alpha[r];
            o1[r] *= alpha[r];
        }
        // P (C-layout) -> LDS -> A-layout, wave-local (DS ops in-order per wave; fence for safety)
        #pragma unroll
        for (int r = 0; r < 4; r++) {
            Pw[wave][q4 * 4 + r][lr] = f2bf(sc0[r]);
            Pw[wave][q4 * 4 + r][16 + lr] = f2bf(sc1[r]);
        }
        asm volatile("s_waitcnt lgkmcnt(0)" ::: "memory");
        bf16x8 pf = *(const bf16x8*)&Pw[wave][lr][q4 * 8];
        bf16x8 vf0 = *(const bf16x8*)&Vt[lr][n0 + q4 * 8];
        bf16x8 vf1 = *(const bf16x8*)&Vt[16 + lr][n0 + q4 * 8];
        o0 = __builtin_amdgcn_mfma_f32_16x16x32_bf16(pf, vf0, o0, 0, 0, 0);
        o1 = __builtin_amdgcn_mfma_f32_16x16x32_bf16(pf, vf1, o1, 0, 0, 0);
    }

    #pragma unroll
    for (int r = 0; r < 4; r++) {
        float inv = 1.f / l[r];
        int krow = kbase + q4 * 4 + r;
        float* op = out + ((size_t)(b * KK + krow)) * D + h * DH;
        op[lr] = o0[r] * inv;
        op[16 + lr] = o1[r] * inv;
    }
}

extern "C" void kernel_launch(void* const* d_in, const int* in_sizes, int n_in,
                              void* d_out, int out_size, void* d_ws, size_t ws_size,
                              hipStream_t stream) {
    const float* meas_xy = (const float*)d_in[0];
    const float* meas_v  = (const float*)d_in[1];
    const float* bs_xy   = (const float*)d_in[2];
    const int*   task_id = (const int*)d_in[3];
    const float* city    = (const float*)d_in[4];
    const float* mp_w1 = (const float*)d_in[5];  const float* mp_b1 = (const float*)d_in[6];
    const float* mp_w2 = (const float*)d_in[7];  const float* mp_b2 = (const float*)d_in[8];
    const float* bp_w1 = (const float*)d_in[9];  const float* bp_b1 = (const float*)d_in[10];
    const float* bp_w2 = (const float*)d_in[11]; const float* bp_b2 = (const float*)d_in[12];
    const float* env_w1 = (const float*)d_in[13]; const float* env_b1 = (const float*)d_in[14];
    const float* env_w2 = (const float*)d_in[15]; const float* env_b2 = (const float*)d_in[16];
    const float* env_w3 = (const float*)d_in[17]; const float* env_b3 = (const float*)d_in[18];
    const float* task_emb = (const float*)d_in[19];
    const float* tp_w = (const float*)d_in[20]; const float* tp_b = (const float*)d_in[21];
    const float* grid_pos = (const float*)d_in[22];
    const float* dens_w = (const float*)d_in[23]; const float* dens_b = (const float*)d_in[24];
    const float* ln1_w = (const float*)d_in[25]; const float* ln1_b = (const float*)d_in[26];
    const float* wq = (const float*)d_in[27]; const float* bq = (const float*)d_in[28];
    const float* wk = (const float*)d_in[29]; const float* bk = (const float*)d_in[30];
    const float* wv = (const float*)d_in[31]; const float* bv = (const float*)d_in[32];
    const float* wo = (const float*)d_in[33]; const float* bo = (const float*)d_in[34];
    const float* ln2_w = (const float*)d_in[35]; const float* ln2_b = (const float*)d_in[36];
    const float* ff_w1 = (const float*)d_in[37]; const float* ff_b1 = (const float*)d_in[38];
    const float* ff_w2 = (const float*)d_in[39]; const float* ff_b2 = (const float*)d_in[40];
    const float* tfp_w = (const float*)d_in[41]; const float* tfp_b = (const float*)d_in[42];
    const float* head_w = (const float*)d_in[43]; const float* head_b = (const float*)d_in[44];
    float* out = (float*)d_out;

    float* ws = (float*)d_ws;
    size_t off = 0;
    float* src    = ws + off; off += (size_t)B * NS * D;        // f32 src tokens
    float* src_xy = ws + off; off += (size_t)B * NS * 2 + 128;  // +pad for masked reads
    float* dens   = ws + off; off += (size_t)B * KK;
    float* tvec   = ws + off; off += (size_t)B * D;
    float* h1     = ws + off; off += (size_t)B * EC * KK;
    float* h2     = ws + off; off += (size_t)B * EC * KK;
    float* grid   = ws + off; off += (size_t)B * KK * D;
    float* bufA   = ws + off; off += (size_t)B * KK * D;
    float* bufB   = ws + off; off += (size_t)B * KK * D;        // also hosts qbf (bf16, half size)
    float* kkb    = ws + off; off += (size_t)B * NS * D;        // hosts kbf bf16 (+mask slop)
    float* vvb    = ws + off; off += (size_t)B * NS * D;        // hosts vbf bf16 (+mask slop)
    (void)ws_size; (void)n_in; (void)in_sizes; (void)out_size;

    unsigned short* qbf = (unsigned short*)bufB;
    unsigned short* kbf = (unsigned short*)kkb;
    unsigned short* vbf = (unsigned short*)vvb;

    const int M = B * KK;       // 16384
    const int Msrc = B * NS;    // 2052

    tok_mlp_k<<<B * N + B, 256, 0, stream>>>(meas_xy, meas_v, bs_xy, mp_w1, mp_b1, mp_w2, mp_b2,
                                             bp_w1, bp_b1, bp_w2, bp_b2, src, src_xy);
    density_k<<<B * 16, 256, 0, stream>>>(meas_xy, dens);
    conv1_k<<<(B * EC * KK) / 256, 256, 0, stream>>>(city, env_w1, env_b1, h1);
    conv2_k<<<(B * EC * KK) / 256, 256, 0, stream>>>(h1, env_w2, env_b2, h2);
    tvec_k<<<B, 256, 0, stream>>>(task_emb, task_id, tp_w, tp_b, tvec);
    grid_init_k<<<M, 256, 0, stream>>>(h2, env_w3, env_b3, grid_pos, tvec, grid);

    for (int l = 0; l < LYR; l++) {
        dens_inject_k<<<M, 256, 0, stream>>>(grid, dens, dens_w + l * D, dens_b + l * D);
        ln_k<<<M, 256, 0, stream>>>(grid, ln1_w + l * D, ln1_b + l * D, bufA);
        // q (bf16) = hn @ wq + bq
        gemm_mfma<0, 0, 1><<<dim3(D / 64, M / 64), 256, 0, stream>>>(
            bufA, wq + (size_t)l * D * D, bq + l * D, qbf, M, D, D);
        // k,v (bf16) = src @ wk/wv + b
        gemm_mfma<0, 0, 1><<<dim3(D / 64, (Msrc + 63) / 64), 256, 0, stream>>>(
            src, wk + (size_t)l * D * D, bk + l * D, kbf, Msrc, D, D);
        gemm_mfma<0, 0, 1><<<dim3(D / 64, (Msrc + 63) / 64), 256, 0, stream>>>(
            src, wv + (size_t)l * D * D, bv + l * D, vbf, Msrc, D, D);
        attn_mfma<<<B * NH * 64, 256, 0, stream>>>(qbf, kbf, vbf, src_xy, bufA);
        // grid += attn_out @ wo + bo
        gemm_mfma<0, 1, 0><<<dim3(D / 64, M / 64), 256, 0, stream>>>(
            bufA, wo + (size_t)l * D * D, bo + l * D, grid, M, D, D);
        // FF
        ln_k<<<M, 256, 0, stream>>>(grid, ln2_w + l * D, ln2_b + l * D, bufB);
        for (int c = 0; c < 4; c++) {
            const float* a1 = bufB + (size_t)c * 4096 * D;
            float* gout = grid + (size_t)c * 4096 * D;
            gemm_mfma<1, 0, 0><<<dim3(DFF / 64, 4096 / 64), 256, 0, stream>>>(
                a1, ff_w1 + (size_t)l * D * DFF, ff_b1 + l * DFF, bufA, 4096, D, DFF);
            gemm_mfma<0, 1, 0><<<dim3(D / 64, 4096 / 64), 256, 0, stream>>>(
                bufA, ff_w2 + (size_t)l * DFF * D, ff_b2 + l * D, gout, 4096, DFF, D);
        }
    }
    gemm_task_mfma<<<dim3(D / 64, M / 64), 256, 0, stream>>>(grid, tfp_w, tfp_b, task_id, bufA);
    head_red_k<<<M / 4, 256, 0, stream>>>(bufA, head_w, head_b, out);
}